// Round 7
// baseline (179.470 us; speedup 1.0000x reference)
//
#include <hip/hip_runtime.h>
#include <cmath>

// DeepFM R7 (= R6 + alignment fix in dotj): multi-row pipelined blocks (G=8,
// double-buffered Es), strip-shared MFMA fragments, wide fused into staging.
// fm: C = E_ti x E_tj^T; z += sum C * W2[j][i] (masked i<j<TS)
// deep: C = E_tt x wdT_kt^T (M=t, N=k); z += relu(C+b).W3[k][t] (masked t<TS)
// w_ffn: deep [0,3200)=t*32+k | fm [3200,8150)=triu i<j | wide [8150,14550)=t*64+f

#define TS 100
#define F  64
#define FD 32
#define RP 112
#define G  8
#define OFF_FM 3200
#define OFF_WIDE 8150
#define VOCAB 100000
#define W2_ELEMS (RP*RP)      // [j:112][i:112] fp32
#define W3_ELEMS (FD*RP)      // [k:32][t:112] fp32
#define WDT_ELEMS (FD*F)      // [k:32][f:64] bf16
#define ESTRIDE (RP*F)        // ushorts per Es buffer (14336 B)

typedef __attribute__((ext_vector_type(8))) short short8;
typedef __attribute__((ext_vector_type(4))) float f32x4;

__device__ __forceinline__ ushort f2bf(float x) {
    uint u = __float_as_uint(x);
    u = (u + 0x7FFFu + ((u >> 16) & 1u)) >> 16;
    return (ushort)u;
}
__device__ __forceinline__ float bf2f(ushort h) {
    return __uint_as_float((uint)h << 16);
}

__global__ __launch_bounds__(256)
void emb_cvt(const float* __restrict__ src, ushort* __restrict__ dst, int n8) {
    int i = blockIdx.x * 256 + threadIdx.x;
    if (i >= n8) return;
    const float4* s = reinterpret_cast<const float4*>(src) + (size_t)i * 2;
    float4 a = s[0], b = s[1];
    ushort t[8] = { f2bf(a.x), f2bf(a.y), f2bf(a.z), f2bf(a.w),
                    f2bf(b.x), f2bf(b.y), f2bf(b.z), f2bf(b.w) };
    reinterpret_cast<uint4*>(dst)[i] = *reinterpret_cast<const uint4*>(t);
}

__global__ __launch_bounds__(256)
void prep(const float* __restrict__ w_ffn, const float* __restrict__ w_deep,
          float* __restrict__ W2, float* __restrict__ W3, ushort* __restrict__ wdt) {
    int j = blockIdx.x * 256 + threadIdx.x;
    if (j < W2_ELEMS) {
        int jc = j / RP, i = j % RP;
        float v = 0.f;
        if (i < jc && jc < TS)
            v = w_ffn[OFF_FM + i * (199 - i) / 2 + (jc - i - 1)];
        W2[j] = v;
    } else if (j < W2_ELEMS + W3_ELEMS) {
        int q = j - W2_ELEMS;
        int k = q / RP, t = q % RP;
        W3[q] = (t < TS) ? w_ffn[t * FD + k] : 0.f;
    } else if (j < W2_ELEMS + W3_ELEMS + WDT_ELEMS) {
        int q = j - W2_ELEMS - W3_ELEMS;
        int k = q >> 6, f = q & 63;
        wdt[q] = f2bf(w_deep[f * FD + k]);
    }
}

// fm strip: A = E rows TI*16 (persistent); tiles tj=TI..6; diag tile reuses A as B.
template<int TI>
__device__ __forceinline__ float fm_strip(const char* esp, int c0, int c1,
                                          const float* pW2) {
    short8 A0 = *reinterpret_cast<const short8*>(esp + TI * 2048 + c0);
    short8 A1 = *reinterpret_cast<const short8*>(esp + TI * 2048 + c1);
    float z = 0.f;
    #pragma unroll
    for (int tj = TI; tj < 7; ++tj) {
        short8 B0, B1;
        if (tj == TI) { B0 = A0; B1 = A1; }
        else {
            B0 = *reinterpret_cast<const short8*>(esp + tj * 2048 + c0);
            B1 = *reinterpret_cast<const short8*>(esp + tj * 2048 + c1);
        }
        f32x4 acc = {0.f, 0.f, 0.f, 0.f};
        acc = __builtin_amdgcn_mfma_f32_16x16x32_bf16(A0, B0, acc, 0, 0, 0);
        acc = __builtin_amdgcn_mfma_f32_16x16x32_bf16(A1, B1, acc, 0, 0, 0);
        float4 w = *reinterpret_cast<const float4*>(pW2 + tj * 1792 + TI * 16);
        z += acc[0] * w.x + acc[1] * w.y + acc[2] * w.z + acc[3] * w.w;
    }
    return z;
}

// deep strip: B = wdT rows KT*16 (persistent); A = E rows tt (M=t, N=k).
template<int KT>
__device__ __forceinline__ float deep_strip(const char* esp, const char* wdp,
                                            int c0, int c1, const float* pW3,
                                            float bk) {
    short8 B0 = *reinterpret_cast<const short8*>(wdp + KT * 2048 + c0);
    short8 B1 = *reinterpret_cast<const short8*>(wdp + KT * 2048 + c1);
    float z = 0.f;
    #pragma unroll
    for (int tt = 0; tt < 7; ++tt) {
        short8 A0 = *reinterpret_cast<const short8*>(esp + tt * 2048 + c0);
        short8 A1 = *reinterpret_cast<const short8*>(esp + tt * 2048 + c1);
        f32x4 acc = {0.f, 0.f, 0.f, 0.f};
        acc = __builtin_amdgcn_mfma_f32_16x16x32_bf16(A0, B0, acc, 0, 0, 0);
        acc = __builtin_amdgcn_mfma_f32_16x16x32_bf16(A1, B1, acc, 0, 0, 0);
        float4 w = *reinterpret_cast<const float4*>(pW3 + KT * 1792 + tt * 16);
        z += fmaxf(acc[0] + bk, 0.f) * w.x + fmaxf(acc[1] + bk, 0.f) * w.y
           + fmaxf(acc[2] + bk, 0.f) * w.z + fmaxf(acc[3] + bk, 0.f) * w.w;
    }
    return z;
}

template<bool EMBBF>
__device__ __forceinline__ uint4 load8(const float* __restrict__ embf,
                                       const ushort* __restrict__ embh,
                                       int xr, int k8) {
    if (EMBBF) {
        return *reinterpret_cast<const uint4*>(embh + (size_t)xr * F + k8 * 8);
    } else {
        const float* s = embf + (size_t)xr * F + k8 * 8;
        float4 a = reinterpret_cast<const float4*>(s)[0];
        float4 c = reinterpret_cast<const float4*>(s)[1];
        ushort t[8] = { f2bf(a.x), f2bf(a.y), f2bf(a.z), f2bf(a.w),
                        f2bf(c.x), f2bf(c.y), f2bf(c.z), f2bf(c.w) };
        return *reinterpret_cast<const uint4*>(t);
    }
}

// wide dot for one 8-elem slice; w_ffn wide base is only 8B-aligned -> float2
__device__ __forceinline__ float dotj(uint4 v, const float* __restrict__ w) {
    short8 sv = *reinterpret_cast<const short8*>(&v);
    const float2* w2 = reinterpret_cast<const float2*>(w);
    float2 wa = w2[0], wb = w2[1], wc = w2[2], wd = w2[3];
    return bf2f((ushort)sv[0]) * wa.x + bf2f((ushort)sv[1]) * wa.y
         + bf2f((ushort)sv[2]) * wb.x + bf2f((ushort)sv[3]) * wb.y
         + bf2f((ushort)sv[4]) * wc.x + bf2f((ushort)sv[5]) * wc.y
         + bf2f((ushort)sv[6]) * wd.x + bf2f((ushort)sv[7]) * wd.y;
}

template<bool EMBBF>
__global__ __launch_bounds__(256, 4)
void deepfm_main(const int* __restrict__ x,
                 const float* __restrict__ embf,
                 const ushort* __restrict__ embh,
                 const float* __restrict__ W2,
                 const float* __restrict__ W3,
                 const ushort* __restrict__ wdt,
                 const float* __restrict__ b_deep,
                 const float* __restrict__ w_ffn,
                 const float* __restrict__ b_ffn,
                 float* __restrict__ out)
{
    __shared__ ushort Es[2][ESTRIDE];   // 2x14336B, XOR-swizzled rows
    __shared__ ushort wdT[FD * F];      // 4096B
    __shared__ int    xsa[G * TS];      // 3200B
    __shared__ float  red[G][4];

    const int tid  = threadIdx.x;
    const int lane = tid & 63;
    const int wave = tid >> 6;
    const int lr   = lane & 15;
    const int lg   = lane >> 4;
    const int b0   = blockIdx.x * G;

    // stage row indices for all G rows + wdT
    for (int j = tid; j < G * TS; j += 256) xsa[j] = x[(size_t)b0 * TS + j];
    {
        int k = tid >> 3, k8 = tid & 7;
        int col = (k8 * 16) ^ ((k & 7) << 4);
        *reinterpret_cast<uint4*>(reinterpret_cast<char*>(wdT) + k * 128 + col)
            = *reinterpret_cast<const uint4*>(wdt + k * F + k8 * 8);
    }
    __syncthreads();

    // fixed per-thread gather geometry: jobs j = tid, tid+256, tid+512, tid+768
    const int k8  = tid & 7;
    const int r0  = tid >> 3;                 // job rows: r0, r0+32, r0+64, r0+96
    const int sw  = (r0 & 7) << 4;            // (r+32k)&7 == r&7
    const int col = (k8 * 16) ^ sw;
    const bool has3  = tid < 128;             // rows 96..111
    const bool real3 = tid < 32;              // rows 96..99
    const float* ww0 = w_ffn + OFF_WIDE + (r0)      * F + k8 * 8;
    const float* ww1 = w_ffn + OFF_WIDE + (r0 + 32) * F + k8 * 8;
    const float* ww2 = w_ffn + OFF_WIDE + (r0 + 64) * F + k8 * 8;
    const float* ww3 = real3 ? (w_ffn + OFF_WIDE + (r0 + 96) * F + k8 * 8) : nullptr;

    // fragment/epilogue bases
    const int c0 = (lg * 16) ^ ((lr & 7) << 4);
    const int c1 = (64 + lg * 16) ^ ((lr & 7) << 4);
    const char* wdp = reinterpret_cast<const char*>(wdT) + lr * 128;
    const float* pW2 = W2 + lr * RP + lg * 4;
    const float* pW3 = W3 + lr * RP + lg * 4;
    const float bk0 = b_deep[lr];
    const float bk1 = b_deep[16 + lr];

    // ---- prologue: gather + wide + stage row 0 ----
    float zw_pend;
    {
        uint4 v0 = load8<EMBBF>(embf, embh, xsa[r0], k8);
        uint4 v1 = load8<EMBBF>(embf, embh, xsa[r0 + 32], k8);
        uint4 v2 = load8<EMBBF>(embf, embh, xsa[r0 + 64], k8);
        uint4 v3 = make_uint4(0, 0, 0, 0);
        if (real3) v3 = load8<EMBBF>(embf, embh, xsa[r0 + 96], k8);
        zw_pend = dotj(v0, ww0) + dotj(v1, ww1) + dotj(v2, ww2);
        if (real3) zw_pend += dotj(v3, ww3);
        char* base = reinterpret_cast<char*>(Es[0]);
        *reinterpret_cast<uint4*>(base + (r0)      * 128 + col) = v0;
        *reinterpret_cast<uint4*>(base + (r0 + 32) * 128 + col) = v1;
        *reinterpret_cast<uint4*>(base + (r0 + 64) * 128 + col) = v2;
        if (has3) *reinterpret_cast<uint4*>(base + (r0 + 96) * 128 + col) = v3;
    }
    __syncthreads();

    // ---- main pipelined loop over G rows ----
    for (int g = 0; g < G; ++g) {
        const int cur = g & 1;
        uint4 v0, v1, v2, v3 = make_uint4(0, 0, 0, 0);
        if (g < G - 1) {
            const int* xg = xsa + (g + 1) * TS;
            v0 = load8<EMBBF>(embf, embh, xg[r0], k8);
            v1 = load8<EMBBF>(embf, embh, xg[r0 + 32], k8);
            v2 = load8<EMBBF>(embf, embh, xg[r0 + 64], k8);
            if (real3) v3 = load8<EMBBF>(embf, embh, xg[r0 + 96], k8);
        }

        const char* esp = reinterpret_cast<const char*>(Es[cur]) + lr * 128;
        float z = zw_pend;
        switch (wave) {
            case 0: z += fm_strip<0>(esp, c0, c1, pW2)
                       + fm_strip<4>(esp, c0, c1, pW2); break;
            case 1: z += fm_strip<1>(esp, c0, c1, pW2)
                       + fm_strip<5>(esp, c0, c1, pW2)
                       + fm_strip<6>(esp, c0, c1, pW2); break;
            case 2: z += fm_strip<2>(esp, c0, c1, pW2)
                       + deep_strip<0>(esp, wdp, c0, c1, pW3, bk0); break;
            default: z += fm_strip<3>(esp, c0, c1, pW2)
                       + deep_strip<1>(esp, wdp, c0, c1, pW3, bk1); break;
        }

        if (g < G - 1) {
            zw_pend = dotj(v0, ww0) + dotj(v1, ww1) + dotj(v2, ww2);
            if (real3) zw_pend += dotj(v3, ww3);
            char* base = reinterpret_cast<char*>(Es[cur ^ 1]);
            *reinterpret_cast<uint4*>(base + (r0)      * 128 + col) = v0;
            *reinterpret_cast<uint4*>(base + (r0 + 32) * 128 + col) = v1;
            *reinterpret_cast<uint4*>(base + (r0 + 64) * 128 + col) = v2;
            if (has3) *reinterpret_cast<uint4*>(base + (r0 + 96) * 128 + col) = v3;
        }

        #pragma unroll
        for (int off = 32; off > 0; off >>= 1) z += __shfl_down(z, off, 64);
        if (lane == 0) red[g][wave] = z;
        __syncthreads();
    }

    if (tid < G) {
        float s = red[tid][0] + red[tid][1] + red[tid][2] + red[tid][3] + b_ffn[0];
        out[b0 + tid] = 1.f / (1.f + expf(-s));
    }
}

extern "C" void kernel_launch(void* const* d_in, const int* in_sizes, int n_in,
                              void* d_out, int out_size, void* d_ws, size_t ws_size,
                              hipStream_t stream) {
    const int*   x      = (const int*)  d_in[0];
    const float* emb    = (const float*)d_in[1];
    const float* w_deep = (const float*)d_in[2];
    const float* b_deep = (const float*)d_in[3];
    const float* w_ffn  = (const float*)d_in[4];
    const float* b_ffn  = (const float*)d_in[5];
    float* out = (float*)d_out;
    const int bs = in_sizes[0] / TS;                         // 8192
    const int nblk = bs / G;                                 // 1024
    const size_t embh_bytes = (size_t)VOCAB * F * 2;         // 12.8 MB
    const size_t w2_bytes = W2_ELEMS * 4;
    const size_t w3_bytes = W3_ELEMS * 4;
    const size_t wdt_bytes = WDT_ELEMS * 2;
    const size_t wtot = w2_bytes + w3_bytes + wdt_bytes;
    const int prep_jobs = W2_ELEMS + W3_ELEMS + WDT_ELEMS;

    if (ws_size >= embh_bytes + wtot) {
        ushort* embhp = (ushort*)d_ws;
        float*  W2p   = (float*)((char*)d_ws + embh_bytes);
        float*  W3p   = (float*)((char*)d_ws + embh_bytes + w2_bytes);
        ushort* wdtp  = (ushort*)((char*)d_ws + embh_bytes + w2_bytes + w3_bytes);
        const int n8 = VOCAB * F / 8;
        hipLaunchKernelGGL(emb_cvt, dim3((n8 + 255) / 256), dim3(256), 0, stream,
                           emb, embhp, n8);
        hipLaunchKernelGGL(prep, dim3((prep_jobs + 255) / 256), dim3(256), 0, stream,
                           w_ffn, w_deep, W2p, W3p, wdtp);
        hipLaunchKernelGGL((deepfm_main<true>), dim3(nblk), dim3(256), 0, stream,
                           x, emb, embhp, W2p, W3p, wdtp, b_deep, w_ffn, b_ffn, out);
    } else {
        float*  W2p  = (float*)d_ws;
        float*  W3p  = (float*)((char*)d_ws + w2_bytes);
        ushort* wdtp = (ushort*)((char*)d_ws + w2_bytes + w3_bytes);
        hipLaunchKernelGGL(prep, dim3((prep_jobs + 255) / 256), dim3(256), 0, stream,
                           w_ffn, w_deep, W2p, W3p, wdtp);
        hipLaunchKernelGGL((deepfm_main<false>), dim3(nblk), dim3(256), 0, stream,
                           x, emb, (const ushort*)nullptr, W2p, W3p, wdtp,
                           b_deep, w_ffn, b_ffn, out);
    }
}